// Round 1
// baseline (226.651 us; speedup 1.0000x reference)
//
#include <hip/hip_runtime.h>

typedef __attribute__((ext_vector_type(8))) __bf16 bf16x8;
typedef __attribute__((ext_vector_type(8))) unsigned short u16x8;
typedef __attribute__((ext_vector_type(4))) unsigned short u16x4;
typedef __attribute__((ext_vector_type(4))) float f32x4;

__device__ __forceinline__ unsigned short f2bf(float f) {
  union { float f; unsigned u; } c; c.f = f;
  unsigned r = c.u + 0x7FFFu + ((c.u >> 16) & 1u);   // round-to-nearest-even
  return (unsigned short)(r >> 16);
}

__device__ __forceinline__ f32x4 mfma16(bf16x8 a, bf16x8 b, f32x4 c) {
  return __builtin_amdgcn_mfma_f32_16x16x32_bf16(a, b, c, 0, 0, 0);
}

__device__ __forceinline__ bf16x8 ld_frag(const unsigned short* p) {
  return __builtin_bit_cast(bf16x8, *(const u16x8*)p);
}

// ---------------------------------------------------------------------------
// K0: A = A_low@A_high, A^2..A^4, export f32 + bf16 copies, sigma_max(A)
// ---------------------------------------------------------------------------
__global__ __launch_bounds__(256) void k0_prep(const float* __restrict__ Al,
                                               const float* __restrict__ Ah,
                                               float* __restrict__ akf,
                                               unsigned short* __restrict__ akb,
                                               float* __restrict__ spec) {
  __shared__ float A[4][64][68];
  __shared__ float Alo[64][36];
  __shared__ float Ahi[32][68];
  const int tid = threadIdx.x, lane = tid & 63, wq = tid >> 6;
  for (int f = tid; f < 512; f += 256) {
    int r = f >> 3, c = (f & 7) << 2;
    *(f32x4*)&Alo[r][c] = *(const f32x4*)&Al[r * 32 + c];
  }
  for (int f = tid; f < 512; f += 256) {
    int r = f >> 4, c = (f & 15) << 2;
    *(f32x4*)&Ahi[r][c] = *(const f32x4*)&Ah[r * 64 + c];
  }
  __syncthreads();
  {
    float ar[32];
#pragma unroll
    for (int r = 0; r < 32; r++) ar[r] = Alo[lane][r];
#pragma unroll
    for (int m4 = 0; m4 < 4; m4++) {
      f32x4 s = {0.f, 0.f, 0.f, 0.f};
#pragma unroll
      for (int r = 0; r < 32; r++)
        s += ar[r] * *(const f32x4*)&Ahi[r][wq * 16 + m4 * 4];
      *(f32x4*)&A[0][lane][wq * 16 + m4 * 4] = s;
    }
  }
  __syncthreads();
  for (int p = 1; p < 4; p++) {          // A^{p+1} = A^p * A
    float ar[64];
#pragma unroll
    for (int k = 0; k < 64; k++) ar[k] = A[p - 1][lane][k];
#pragma unroll
    for (int m4 = 0; m4 < 4; m4++) {
      f32x4 s = {0.f, 0.f, 0.f, 0.f};
#pragma unroll
      for (int k = 0; k < 64; k++)
        s += ar[k] * *(const f32x4*)&A[0][k][wq * 16 + m4 * 4];
      *(f32x4*)&A[p][lane][wq * 16 + m4 * 4] = s;
    }
    __syncthreads();
  }
  for (int f = tid; f < 16384; f += 256) {   // export [k][n][m]
    int k = f >> 12, n = (f >> 6) & 63, m = f & 63;
    float v = A[k][n][m];
    akf[f] = v;
    akb[f] = f2bf(v);
  }
  if (wq == 0) {   // power iteration on A^T A, wave 0 only
    float ar[64], at[64];
#pragma unroll
    for (int m = 0; m < 64; m++) { ar[m] = A[0][lane][m]; at[m] = A[0][m][lane]; }
    float v = 1.0f + 0.001f * (float)lane;
    for (int it = 0; it < 20; it++) {
      float w = 0.f;
#pragma unroll
      for (int m = 0; m < 64; m++) w += ar[m] * __shfl(v, m, 64);
      float z = 0.f;
#pragma unroll
      for (int m = 0; m < 64; m++) z += at[m] * __shfl(w, m, 64);
      float ss = z * z;
#pragma unroll
      for (int off = 32; off; off >>= 1) ss += __shfl_xor(ss, off, 64);
      v = z * rsqrtf(ss + 1e-38f);
    }
    float w = 0.f;
#pragma unroll
    for (int m = 0; m < 64; m++) w += ar[m] * __shfl(v, m, 64);
    float ss = w * w;
#pragma unroll
    for (int off = 32; off; off >>= 1) ss += __shfl_xor(ss, off, 64);
    if (lane == 0) *spec = sqrtf(ss);
  }
}

// ---------------------------------------------------------------------------
// G1: u[t][n] = (sum_d x[t][d]*Bw[n][d] + Bb[n]) * rw[t]   (bf16 MFMA)
// ---------------------------------------------------------------------------
__global__ __launch_bounds__(256) void g1_gemm(const float* __restrict__ x,
                                               const float* __restrict__ Bw,
                                               const float* __restrict__ Bb,
                                               const float* __restrict__ rw,
                                               float* __restrict__ u) {
  __shared__ __align__(16) unsigned short xs[64][72];
  __shared__ __align__(16) unsigned short bs[64][72];
  const int tid = threadIdx.x, lane = tid & 63, wid = tid >> 6;
  const int t0 = blockIdx.x * 64;
  f32x4 acc[4];
#pragma unroll
  for (int n = 0; n < 4; n++) acc[n] = f32x4{0.f, 0.f, 0.f, 0.f};
  const int arow = wid * 16 + (lane & 15);
  const int kcol = (lane >> 4) * 8;
  for (int k0 = 0; k0 < 1024; k0 += 64) {
#pragma unroll
    for (int i = 0; i < 4; i++) {
      int f = tid + 256 * i;
      int row = f >> 4, c4 = (f & 15) << 2;
      f32x4 v = *(const f32x4*)&x[(size_t)(t0 + row) * 1024 + k0 + c4];
      u16x4 b; b[0] = f2bf(v[0]); b[1] = f2bf(v[1]); b[2] = f2bf(v[2]); b[3] = f2bf(v[3]);
      *(u16x4*)&xs[row][c4] = b;
      f32x4 w = *(const f32x4*)&Bw[(size_t)row * 1024 + k0 + c4];
      u16x4 bw; bw[0] = f2bf(w[0]); bw[1] = f2bf(w[1]); bw[2] = f2bf(w[2]); bw[3] = f2bf(w[3]);
      *(u16x4*)&bs[row][c4] = bw;
    }
    __syncthreads();
#pragma unroll
    for (int kk = 0; kk < 2; kk++) {
      bf16x8 a = ld_frag(&xs[arow][kk * 32 + kcol]);
#pragma unroll
      for (int n = 0; n < 4; n++) {
        bf16x8 b = ld_frag(&bs[n * 16 + (lane & 15)][kk * 32 + kcol]);
        acc[n] = mfma16(a, b, acc[n]);
      }
    }
    __syncthreads();
  }
  const int r0 = wid * 16 + ((lane >> 4) << 2);
#pragma unroll
  for (int n = 0; n < 4; n++) {
    int col = n * 16 + (lane & 15);
    float bb = Bb[col];
#pragma unroll
    for (int j = 0; j < 4; j++) {
      int t = t0 + r0 + j;
      u[(size_t)t * 64 + col] = (acc[n][j] + bb) * rw[t];
    }
  }
}

// ---------------------------------------------------------------------------
// K2: hs[t] = u[t] + sum_{k=1..4} A^k u[t-k]  (MFMA, 4 shifted slabs,
//     batch boundaries handled by zero-staging out-of-batch rows)
// ---------------------------------------------------------------------------
__global__ __launch_bounds__(256) void k2_hs(const float* __restrict__ u,
                                             const unsigned short* __restrict__ akb,
                                             unsigned short* __restrict__ hs) {
  __shared__ __align__(16) unsigned short us[132][72];
  __shared__ __align__(16) unsigned short wt[4][64][72];
  const int tid = threadIdx.x, lane = tid & 63, wid = tid >> 6;
  const int t0 = blockIdx.x * 128;
  const int bstart = t0 & ~4095;
  for (int f = tid; f < 2112; f += 256) {        // 132 rows x 64 cols
    int row = f >> 4, c4 = (f & 15) << 2;
    int g = t0 - 4 + row;
    f32x4 v = {0.f, 0.f, 0.f, 0.f};
    if (g >= bstart) v = *(const f32x4*)&u[(size_t)g * 64 + c4];
    u16x4 b; b[0] = f2bf(v[0]); b[1] = f2bf(v[1]); b[2] = f2bf(v[2]); b[3] = f2bf(v[3]);
    *(u16x4*)&us[row][c4] = b;
  }
  for (int f = tid; f < 4096; f += 256) {        // A^1..A^4 bf16 [k][n][m]
    int e = f << 2;
    int k = e >> 12, n = (e >> 6) & 63, m = e & 63;
    *(u16x4*)&wt[k][n][m] = *(const u16x4*)&akb[e];
  }
  __syncthreads();
  f32x4 acc[2][4];
#pragma unroll
  for (int m = 0; m < 2; m++)
#pragma unroll
    for (int n = 0; n < 4; n++) acc[m][n] = f32x4{0.f, 0.f, 0.f, 0.f};
  const int kcol = (lane >> 4) * 8;
#pragma unroll
  for (int k = 0; k < 4; k++) {
#pragma unroll
    for (int kk = 0; kk < 2; kk++) {
      bf16x8 b[4];
#pragma unroll
      for (int n = 0; n < 4; n++)
        b[n] = ld_frag(&wt[k][n * 16 + (lane & 15)][kk * 32 + kcol]);
#pragma unroll
      for (int m = 0; m < 2; m++) {
        int lrow = wid * 32 + m * 16 + (lane & 15);
        bf16x8 a = ld_frag(&us[lrow + 3 - k][kk * 32 + kcol]);  // shift k+1
#pragma unroll
        for (int n = 0; n < 4; n++) acc[m][n] = mfma16(a, b[n], acc[m][n]);
      }
    }
  }
#pragma unroll
  for (int m = 0; m < 2; m++) {
#pragma unroll
    for (int n = 0; n < 4; n++) {
      int col = n * 16 + (lane & 15);
#pragma unroll
      for (int j = 0; j < 4; j++) {
        int lrow = wid * 32 + m * 16 + ((lane >> 4) << 2) + j;
        int t = t0 + lrow;
        float val = acc[m][n][j] + u[(size_t)t * 64 + col];   // identity term in f32
        hs[(size_t)t * 64 + col] = f2bf(val);
      }
    }
  }
}

// ---------------------------------------------------------------------------
// K4: state_norm_mean from u (f32) and A^k (f32)
// ---------------------------------------------------------------------------
__global__ __launch_bounds__(64) void k4_norm(const float* __restrict__ u,
                                              const float* __restrict__ akf,
                                              float* __restrict__ out_norm) {
  const int lane = threadIdx.x;
  float sum = 0.f;
  for (int b = 0; b < 8; b++) {
    size_t base = ((size_t)b * 4096 + 4095) * 64;
    float h = u[base + lane];
    for (int k = 1; k <= 4; k++) {
      const float* arow = &akf[(size_t)((k - 1) * 64 + lane) * 64];
      const float* urow = &u[base - (size_t)k * 64];
#pragma unroll
      for (int m = 0; m < 64; m += 4) {
        f32x4 a = *(const f32x4*)&arow[m];
        f32x4 uu = *(const f32x4*)&urow[m];
        h += a[0] * uu[0] + a[1] * uu[1] + a[2] * uu[2] + a[3] * uu[3];
      }
    }
    float ss = h * h;
#pragma unroll
    for (int off = 32; off; off >>= 1) ss += __shfl_xor(ss, off, 64);
    sum += sqrtf(ss);
  }
  if (lane == 0) *out_norm = sum * 0.125f;
}

// ---------------------------------------------------------------------------
// G2: out[t][d] = sum_n hs[t][n]*Cw[d][n] + Cb[d] + D[d]*x[t][d]
// ---------------------------------------------------------------------------
__global__ __launch_bounds__(256) void g2_gemm(const unsigned short* __restrict__ hsb,
                                               const float* __restrict__ Cw,
                                               const float* __restrict__ Cb,
                                               const float* __restrict__ Dv,
                                               const float* __restrict__ x,
                                               float* __restrict__ out) {
  __shared__ __align__(16) unsigned short hss[128][72];
  __shared__ __align__(16) unsigned short cs[128][72];
  const int tid = threadIdx.x, lane = tid & 63, wid = tid >> 6;
  const int t0 = blockIdx.x * 128, d0 = blockIdx.y * 128;
  const int wm = wid >> 1, wn = wid & 1;
#pragma unroll
  for (int i = 0; i < 8; i++) {
    int f = tid + 256 * i;
    int row = f >> 4, c4 = (f & 15) << 2;
    *(u16x4*)&hss[row][c4] = *(const u16x4*)&hsb[(size_t)(t0 + row) * 64 + c4];
    f32x4 v = *(const f32x4*)&Cw[(size_t)(d0 + row) * 64 + c4];
    u16x4 b; b[0] = f2bf(v[0]); b[1] = f2bf(v[1]); b[2] = f2bf(v[2]); b[3] = f2bf(v[3]);
    *(u16x4*)&cs[row][c4] = b;
  }
  __syncthreads();
  f32x4 acc[4][4];
#pragma unroll
  for (int m = 0; m < 4; m++)
#pragma unroll
    for (int n = 0; n < 4; n++) acc[m][n] = f32x4{0.f, 0.f, 0.f, 0.f};
  const int kcol = (lane >> 4) * 8;
#pragma unroll
  for (int kk = 0; kk < 2; kk++) {
    bf16x8 a[4], b[4];
#pragma unroll
    for (int m = 0; m < 4; m++)
      a[m] = ld_frag(&hss[wm * 64 + m * 16 + (lane & 15)][kk * 32 + kcol]);
#pragma unroll
    for (int n = 0; n < 4; n++)
      b[n] = ld_frag(&cs[wn * 64 + n * 16 + (lane & 15)][kk * 32 + kcol]);
#pragma unroll
    for (int m = 0; m < 4; m++)
#pragma unroll
      for (int n = 0; n < 4; n++) acc[m][n] = mfma16(a[m], b[n], acc[m][n]);
  }
#pragma unroll
  for (int m = 0; m < 4; m++) {
#pragma unroll
    for (int n = 0; n < 4; n++) {
      int col = wn * 64 + n * 16 + (lane & 15);
      int d = d0 + col;
      float cb = Cb[d], dd = Dv[d];
#pragma unroll
      for (int j = 0; j < 4; j++) {
        int row = wm * 64 + m * 16 + ((lane >> 4) << 2) + j;
        size_t idx = (size_t)(t0 + row) * 1024 + d;
        out[idx] = acc[m][n][j] + cb + dd * x[idx];
      }
    }
  }
}

extern "C" void kernel_launch(void* const* d_in, const int* in_sizes, int n_in,
                              void* d_out, int out_size, void* d_ws, size_t ws_size,
                              hipStream_t stream) {
  const float* x  = (const float*)d_in[0];
  const float* rw = (const float*)d_in[1];
  const float* Al = (const float*)d_in[2];
  const float* Ah = (const float*)d_in[3];
  const float* Bw = (const float*)d_in[4];
  const float* Bb = (const float*)d_in[5];
  const float* Cw = (const float*)d_in[6];
  const float* Cb = (const float*)d_in[7];
  const float* Dv = (const float*)d_in[8];
  float* out = (float*)d_out;

  char* ws = (char*)d_ws;
  float*          akf = (float*)ws;                                // 64 KiB
  unsigned short* akb = (unsigned short*)(ws + 65536);             // 32 KiB
  float*          u   = (float*)(ws + 98304);                      // 8 MiB
  unsigned short* hsb = (unsigned short*)(ws + 98304 + 8388608);   // 4 MiB

  float* norm_out = out + (out_size - 2);
  float* spec_out = out + (out_size - 1);

  k0_prep<<<dim3(1), dim3(256), 0, stream>>>(Al, Ah, akf, akb, spec_out);
  g1_gemm<<<dim3(512), dim3(256), 0, stream>>>(x, Bw, Bb, rw, u);
  k2_hs<<<dim3(256), dim3(256), 0, stream>>>(u, akb, hsb);
  k4_norm<<<dim3(1), dim3(64), 0, stream>>>(u, akf, norm_out);
  g2_gemm<<<dim3(256, 8), dim3(256), 0, stream>>>(hsb, Cw, Cb, Dv, x, out);
}

// Round 2
// 111.683 us; speedup vs baseline: 2.0294x; 2.0294x over previous
//
#include <hip/hip_runtime.h>

typedef __attribute__((ext_vector_type(8))) __bf16 bf16x8;
typedef __attribute__((ext_vector_type(8))) unsigned short u16x8;
typedef __attribute__((ext_vector_type(4))) float f32x4;

__device__ __forceinline__ f32x4 mfma16(bf16x8 a, bf16x8 b, f32x4 c) {
  return __builtin_amdgcn_mfma_f32_16x16x32_bf16(a, b, c, 0, 0, 0);
}

__device__ __forceinline__ bf16x8 cvt8(f32x4 a, f32x4 b) {
  bf16x8 r;
  r[0] = (__bf16)a[0]; r[1] = (__bf16)a[1]; r[2] = (__bf16)a[2]; r[3] = (__bf16)a[3];
  r[4] = (__bf16)b[0]; r[5] = (__bf16)b[1]; r[6] = (__bf16)b[2]; r[7] = (__bf16)b[3];
  return r;
}

__device__ __forceinline__ unsigned short bf1(float f) {
  return __builtin_bit_cast(unsigned short, (__bf16)f);
}

__device__ __forceinline__ bf16x8 ld_frag(const unsigned short* p) {
  return __builtin_bit_cast(bf16x8, *(const u16x8*)p);
}

// ---------------------------------------------------------------------------
// kfrag: pre-convert Bw and Cw to bf16 MFMA B-fragment layout.
//   BwF entry g = (kstep*4+nt)*64+lane holds Bw[n=nt*16+(l&15)][k=kstep*32+(l>>4)*8 ..+7]
//   CwF entry g = (dt*2+kk)*64+lane    holds Cw[d=dt*16+(l&15)][n=kk*32+(l>>4)*8 ..+7]
// ---------------------------------------------------------------------------
__global__ __launch_bounds__(256) void kfrag(const float* __restrict__ Bw,
                                             const float* __restrict__ Cw,
                                             unsigned short* __restrict__ BwF,
                                             unsigned short* __restrict__ CwF) {
  const int bid = blockIdx.x, tid = threadIdx.x;
  if (bid < 32) {
    int g = bid * 256 + tid;                   // [0, 8192)
    int kstep = g >> 8, nt = (g >> 6) & 3, ln = g & 63;
    int n = nt * 16 + (ln & 15);
    int k = kstep * 32 + (ln >> 4) * 8;
    f32x4 a = *(const f32x4*)&Bw[(size_t)n * 1024 + k];
    f32x4 b = *(const f32x4*)&Bw[(size_t)n * 1024 + k + 4];
    *(u16x8*)&BwF[(size_t)g * 8] = __builtin_bit_cast(u16x8, cvt8(a, b));
  } else {
    int g = (bid - 32) * 256 + tid;            // [0, 8192)
    int dt = g >> 7, kk = (g >> 6) & 1, ln = g & 63;
    int d = dt * 16 + (ln & 15);
    int n = kk * 32 + (ln >> 4) * 8;
    f32x4 a = *(const f32x4*)&Cw[(size_t)d * 64 + n];
    f32x4 b = *(const f32x4*)&Cw[(size_t)d * 64 + n + 4];
    *(u16x8*)&CwF[(size_t)g * 8] = __builtin_bit_cast(u16x8, cvt8(a, b));
  }
}

// ---------------------------------------------------------------------------
// K0: A = A_low@A_high, A^2..A^4 -> bf16 B-fragments (akbF), sigma_max(A),
//     and dflag = max|D| (g2 skips the x re-read when 0).
// ---------------------------------------------------------------------------
__global__ __launch_bounds__(256) void k0_prep(const float* __restrict__ Al,
                                               const float* __restrict__ Ah,
                                               const float* __restrict__ Dv,
                                               unsigned short* __restrict__ akbF,
                                               float* __restrict__ dflag,
                                               float* __restrict__ spec) {
  __shared__ float A[4][64][68];
  __shared__ float Alo[64][36];
  __shared__ float Ahi[32][68];
  const int tid = threadIdx.x, lane = tid & 63, wq = tid >> 6;
  for (int f = tid; f < 512; f += 256) {
    int r = f >> 3, c = (f & 7) << 2;
    *(f32x4*)&Alo[r][c] = *(const f32x4*)&Al[r * 32 + c];
  }
  for (int f = tid; f < 512; f += 256) {
    int r = f >> 4, c = (f & 15) << 2;
    *(f32x4*)&Ahi[r][c] = *(const f32x4*)&Ah[r * 64 + c];
  }
  __syncthreads();
  {
    float ar[32];
#pragma unroll
    for (int r = 0; r < 32; r++) ar[r] = Alo[lane][r];
#pragma unroll
    for (int m4 = 0; m4 < 4; m4++) {
      f32x4 s = {0.f, 0.f, 0.f, 0.f};
#pragma unroll
      for (int r = 0; r < 32; r++)
        s += ar[r] * *(const f32x4*)&Ahi[r][wq * 16 + m4 * 4];
      *(f32x4*)&A[0][lane][wq * 16 + m4 * 4] = s;
    }
  }
  __syncthreads();
  for (int p = 1; p < 4; p++) {                // A^{p+1} = A^p * A
    float ar[64];
#pragma unroll
    for (int k = 0; k < 64; k++) ar[k] = A[p - 1][lane][k];
#pragma unroll
    for (int m4 = 0; m4 < 4; m4++) {
      f32x4 s = {0.f, 0.f, 0.f, 0.f};
#pragma unroll
      for (int k = 0; k < 64; k++)
        s += ar[k] * *(const f32x4*)&A[0][k][wq * 16 + m4 * 4];
      *(f32x4*)&A[p][lane][wq * 16 + m4 * 4] = s;
    }
    __syncthreads();
  }
  // export A^1..A^4 as MFMA B-fragments: e = ((kp*2+kk)*4+nt)*64+lane
#pragma unroll
  for (int i = 0; i < 8; i++) {
    int e = tid + 256 * i;
    int kp = e >> 9, kk = (e >> 8) & 1, nt = (e >> 6) & 3, ln = e & 63;
    int n = nt * 16 + (ln & 15);
    int mc = kk * 32 + (ln >> 4) * 8;
    f32x4 a = *(const f32x4*)&A[kp][n][mc];
    f32x4 b = *(const f32x4*)&A[kp][n][mc + 4];
    *(u16x8*)&akbF[(size_t)e * 8] = __builtin_bit_cast(u16x8, cvt8(a, b));
  }
  if (wq == 0) {   // power iteration on A^T A (8 iters; tolerance is huge)
    float ar[64], at[64];
#pragma unroll
    for (int m = 0; m < 64; m++) { ar[m] = A[0][lane][m]; at[m] = A[0][m][lane]; }
    float v = 1.0f + 0.001f * (float)lane;
    for (int it = 0; it < 8; it++) {
      float w = 0.f;
#pragma unroll
      for (int m = 0; m < 64; m++) w += ar[m] * __shfl(v, m, 64);
      float z = 0.f;
#pragma unroll
      for (int m = 0; m < 64; m++) z += at[m] * __shfl(w, m, 64);
      float ss = z * z;
#pragma unroll
      for (int off = 32; off; off >>= 1) ss += __shfl_xor(ss, off, 64);
      v = z * rsqrtf(ss + 1e-38f);
    }
    float w = 0.f;
#pragma unroll
    for (int m = 0; m < 64; m++) w += ar[m] * __shfl(v, m, 64);
    float ss = w * w;
#pragma unroll
    for (int off = 32; off; off >>= 1) ss += __shfl_xor(ss, off, 64);
    if (lane == 0) *spec = sqrtf(ss);
  }
  if (wq == 1) {   // dflag = max|D|
    float dm = 0.f;
#pragma unroll
    for (int i = 0; i < 16; i++) dm = fmaxf(dm, fabsf(Dv[lane + i * 64]));
#pragma unroll
    for (int off = 32; off; off >>= 1) dm = fmaxf(dm, __shfl_xor(dm, off, 64));
    if (lane == 0) *dflag = dm;
  }
}

// ---------------------------------------------------------------------------
// G1: u[t][n] = (sum_k x[t][k]*Bw[n][k] + Bb[n]) * rw[t]
// One wave per 16 rows; x fragments loaded straight from global (f32->bf16 in
// VALU); B fragments streamed from pre-fragmented BwF. No LDS, no barriers.
// ---------------------------------------------------------------------------
__global__ __launch_bounds__(256) void g1_gemm(const float* __restrict__ x,
                                               const unsigned short* __restrict__ BwF,
                                               const float* __restrict__ Bb,
                                               const float* __restrict__ rw,
                                               float* __restrict__ u) {
  const int tid = threadIdx.x, lane = tid & 63, wid = tid >> 6;
  const int t0 = (blockIdx.x * 4 + wid) * 16;
  const int arow = t0 + (lane & 15);
  const int kc0 = (lane >> 4) * 8;
  f32x4 acc[4];
#pragma unroll
  for (int nt = 0; nt < 4; nt++) acc[nt] = f32x4{0.f, 0.f, 0.f, 0.f};
#pragma unroll 4
  for (int ks = 0; ks < 32; ks++) {
    const float* xp = &x[(size_t)arow * 1024 + ks * 32 + kc0];
    bf16x8 a = cvt8(*(const f32x4*)xp, *(const f32x4*)(xp + 4));
#pragma unroll
    for (int nt = 0; nt < 4; nt++) {
      bf16x8 b = ld_frag(&BwF[((size_t)(ks * 4 + nt) * 64 + lane) * 8]);
      acc[nt] = mfma16(a, b, acc[nt]);
    }
  }
#pragma unroll
  for (int nt = 0; nt < 4; nt++) {
    int col = nt * 16 + (lane & 15);
    float bb = Bb[col];
#pragma unroll
    for (int j = 0; j < 4; j++) {
      int t = t0 + (lane >> 4) * 4 + j;
      u[(size_t)t * 64 + col] = (acc[nt][j] + bb) * rw[t];
    }
  }
}

// ---------------------------------------------------------------------------
// K2: hs[t] = u[t] + sum_{kp=1..4} A^kp u[t-kp]; also accumulates
// state_norm_mean from the f32 batch-end rows (replaces k4).
// One wave per 16 rows, no LDS, no barriers.
// ---------------------------------------------------------------------------
__global__ __launch_bounds__(256) void k2_hs(const float* __restrict__ u,
                                             const unsigned short* __restrict__ akbF,
                                             unsigned short* __restrict__ hsb,
                                             float* __restrict__ norm_out) {
  const int tid = threadIdx.x, lane = tid & 63, wid = tid >> 6;
  const int t0 = (blockIdx.x * 4 + wid) * 16;
  const int bstart = t0 & ~4095;
  const int row = t0 + (lane & 15);
  const int kc0 = (lane >> 4) * 8;
  f32x4 acc[4];
#pragma unroll
  for (int nt = 0; nt < 4; nt++) acc[nt] = f32x4{0.f, 0.f, 0.f, 0.f};
#pragma unroll
  for (int kp = 0; kp < 4; kp++) {
    int g = row - (kp + 1);
#pragma unroll
    for (int kk = 0; kk < 2; kk++) {
      f32x4 xa = {0.f, 0.f, 0.f, 0.f}, xb = {0.f, 0.f, 0.f, 0.f};
      if (g >= bstart) {
        const float* up = &u[(size_t)g * 64 + kk * 32 + kc0];
        xa = *(const f32x4*)up;
        xb = *(const f32x4*)(up + 4);
      }
      bf16x8 a = cvt8(xa, xb);
#pragma unroll
      for (int nt = 0; nt < 4; nt++) {
        bf16x8 b = ld_frag(&akbF[(size_t)(((kp * 2 + kk) * 4 + nt) * 64 + lane) * 8]);
        acc[nt] = mfma16(a, b, acc[nt]);
      }
    }
  }
  float ss = 0.f;
  const bool bend = ((t0 + 15) & 4095) == 4095;   // wave holds a batch-end row
#pragma unroll
  for (int nt = 0; nt < 4; nt++) {
    int col = nt * 16 + (lane & 15);
#pragma unroll
    for (int j = 0; j < 4; j++) {
      int r = t0 + (lane >> 4) * 4 + j;
      float val = acc[nt][j] + u[(size_t)r * 64 + col];   // identity term f32
      hsb[(size_t)r * 64 + col] = bf1(val);
      if (bend && ((lane >> 4) == 3) && (j == 3)) ss += val * val;
    }
  }
  if (bend && (lane >> 4) == 3) {   // lanes 48..63 hold h_last; reduce 16-wide
#pragma unroll
    for (int off = 1; off < 16; off <<= 1) ss += __shfl_xor(ss, off, 64);
    if ((lane & 15) == 0) atomicAdd(norm_out, sqrtf(ss) * 0.125f);
  }
}

// ---------------------------------------------------------------------------
// G2: out[t][d] = sum_n hs[t][n]*Cw[d][n] + Cb[d] + D[d]*x[t][d]
// One wave per 32x64 output tile; hs/CwF fragments direct from global.
// Skips the x read entirely when max|D| == 0 (uniform flag).
// ---------------------------------------------------------------------------
__global__ __launch_bounds__(256) void g2_gemm(const unsigned short* __restrict__ hsb,
                                               const unsigned short* __restrict__ CwF,
                                               const float* __restrict__ Cb,
                                               const float* __restrict__ Dv,
                                               const float* __restrict__ x,
                                               const float* __restrict__ dflag,
                                               float* __restrict__ out) {
  const int tid = threadIdx.x, lane = tid & 63, wid = tid >> 6;
  const int w = blockIdx.x * 4 + wid;
  const int t0 = (w >> 4) * 32, d0 = (w & 15) * 64;
  const int kc0 = (lane >> 4) * 8;
  f32x4 acc[2][4];
#pragma unroll
  for (int m = 0; m < 2; m++)
#pragma unroll
    for (int nt = 0; nt < 4; nt++) acc[m][nt] = f32x4{0.f, 0.f, 0.f, 0.f};
  bf16x8 a[2][2];
#pragma unroll
  for (int m = 0; m < 2; m++)
#pragma unroll
    for (int kk = 0; kk < 2; kk++)
      a[m][kk] = ld_frag(&hsb[(size_t)(t0 + m * 16 + (lane & 15)) * 64 + kk * 32 + kc0]);
#pragma unroll
  for (int nt = 0; nt < 4; nt++)
#pragma unroll
    for (int kk = 0; kk < 2; kk++) {
      bf16x8 b = ld_frag(&CwF[(size_t)((((d0 >> 4) + nt) * 2 + kk) * 64 + lane) * 8]);
#pragma unroll
      for (int m = 0; m < 2; m++) acc[m][nt] = mfma16(a[m][kk], b, acc[m][nt]);
    }
  const bool hasD = (*dflag != 0.0f);
#pragma unroll
  for (int m = 0; m < 2; m++)
#pragma unroll
    for (int nt = 0; nt < 4; nt++) {
      int d = d0 + nt * 16 + (lane & 15);
      float cb = Cb[d], dd = Dv[d];
#pragma unroll
      for (int j = 0; j < 4; j++) {
        int r = t0 + m * 16 + (lane >> 4) * 4 + j;
        size_t idx = (size_t)r * 1024 + d;
        float v = acc[m][nt][j] + cb;
        if (hasD) v += dd * x[idx];
        out[idx] = v;
      }
    }
}

extern "C" void kernel_launch(void* const* d_in, const int* in_sizes, int n_in,
                              void* d_out, int out_size, void* d_ws, size_t ws_size,
                              hipStream_t stream) {
  const float* x  = (const float*)d_in[0];
  const float* rw = (const float*)d_in[1];
  const float* Al = (const float*)d_in[2];
  const float* Ah = (const float*)d_in[3];
  const float* Bw = (const float*)d_in[4];
  const float* Bb = (const float*)d_in[5];
  const float* Cw = (const float*)d_in[6];
  const float* Cb = (const float*)d_in[7];
  const float* Dv = (const float*)d_in[8];
  float* out = (float*)d_out;

  char* ws = (char*)d_ws;
  unsigned short* akbF = (unsigned short*)(ws);                    // 32 KiB
  float*          dflag = (float*)(ws + 32768);                    // 4 B
  unsigned short* BwF  = (unsigned short*)(ws + 65536);            // 128 KiB
  unsigned short* CwF  = (unsigned short*)(ws + 196608);           // 128 KiB
  float*          u    = (float*)(ws + 327680);                    // 8 MiB
  unsigned short* hsb  = (unsigned short*)(ws + 327680 + 8388608); // 4 MiB

  float* norm_out = out + (out_size - 2);
  float* spec_out = out + (out_size - 1);

  kfrag<<<dim3(64), dim3(256), 0, stream>>>(Bw, Cw, BwF, CwF);
  k0_prep<<<dim3(1), dim3(256), 0, stream>>>(Al, Ah, Dv, akbF, dflag, spec_out);
  g1_gemm<<<dim3(512), dim3(256), 0, stream>>>(x, BwF, Bb, rw, u);
  hipMemsetAsync(norm_out, 0, sizeof(float), stream);
  k2_hs<<<dim3(512), dim3(256), 0, stream>>>(u, akbF, hsb, norm_out);
  g2_gemm<<<dim3(4096), dim3(256), 0, stream>>>(hsb, CwF, Cb, Dv, x, dflag, out);
}

// Round 3
// 107.749 us; speedup vs baseline: 2.1035x; 1.0365x over previous
//
#include <hip/hip_runtime.h>

typedef __attribute__((ext_vector_type(8))) __bf16 bf16x8;
typedef __attribute__((ext_vector_type(8))) unsigned short u16x8;
typedef __attribute__((ext_vector_type(4))) unsigned short u16x4;
typedef __attribute__((ext_vector_type(4))) float f32x4;

__device__ __forceinline__ f32x4 mfma16(bf16x8 a, bf16x8 b, f32x4 c) {
  return __builtin_amdgcn_mfma_f32_16x16x32_bf16(a, b, c, 0, 0, 0);
}

__device__ __forceinline__ bf16x8 cvt8(f32x4 a, f32x4 b) {
  bf16x8 r;
  r[0] = (__bf16)a[0]; r[1] = (__bf16)a[1]; r[2] = (__bf16)a[2]; r[3] = (__bf16)a[3];
  r[4] = (__bf16)b[0]; r[5] = (__bf16)b[1]; r[6] = (__bf16)b[2]; r[7] = (__bf16)b[3];
  return r;
}

__device__ __forceinline__ unsigned short bf1(float f) {
  return __builtin_bit_cast(unsigned short, (__bf16)f);
}

__device__ __forceinline__ bf16x8 ld_frag(const unsigned short* p) {
  return __builtin_bit_cast(bf16x8, *(const u16x8*)p);
}

// ---------------------------------------------------------------------------
// kprep: blocks 0..31 -> BwF frags, 32..63 -> CwF frags, block 64 -> A powers
// (akbF frags), sigma_max(A), dflag. Fragment packing (identical for A- and
// B-operand roles of mfma_16x16x32):
//   BwF g=(kstep*4+nt)*64+l : Bw[n=nt*16+(l&15)][k=kstep*32+(l>>4)*8 ..+7]
//   CwF g=(dt*2+kk)*64+l    : Cw[d=dt*16+(l&15)][n=kk*32+(l>>4)*8 ..+7]
//   akbF g=((kp*2+kk)*4+nt)*64+l : A^{kp+1}[n=nt*16+(l&15)][m=kk*32+(l>>4)*8..]
// ---------------------------------------------------------------------------
__global__ __launch_bounds__(256) void kprep(const float* __restrict__ Bw,
                                             const float* __restrict__ Cw,
                                             const float* __restrict__ Al,
                                             const float* __restrict__ Ah,
                                             const float* __restrict__ Dv,
                                             unsigned short* __restrict__ BwF,
                                             unsigned short* __restrict__ CwF,
                                             unsigned short* __restrict__ akbF,
                                             float* __restrict__ dflag,
                                             float* __restrict__ spec) {
  const int bid = blockIdx.x, tid = threadIdx.x;
  if (bid < 32) {
    int g = bid * 256 + tid;
    int kstep = g >> 8, nt = (g >> 6) & 3, ln = g & 63;
    int n = nt * 16 + (ln & 15);
    int k = kstep * 32 + (ln >> 4) * 8;
    f32x4 a = *(const f32x4*)&Bw[(size_t)n * 1024 + k];
    f32x4 b = *(const f32x4*)&Bw[(size_t)n * 1024 + k + 4];
    *(u16x8*)&BwF[(size_t)g * 8] = __builtin_bit_cast(u16x8, cvt8(a, b));
    return;
  }
  if (bid < 64) {
    int g = (bid - 32) * 256 + tid;
    int dt = g >> 7, kk = (g >> 6) & 1, ln = g & 63;
    int d = dt * 16 + (ln & 15);
    int n = kk * 32 + (ln >> 4) * 8;
    f32x4 a = *(const f32x4*)&Cw[(size_t)d * 64 + n];
    f32x4 b = *(const f32x4*)&Cw[(size_t)d * 64 + n + 4];
    *(u16x8*)&CwF[(size_t)g * 8] = __builtin_bit_cast(u16x8, cvt8(a, b));
    return;
  }
  // --- block 64: A = Al@Ah, powers, sigma, dflag ---
  __shared__ float A[4][64][68];
  __shared__ float Alo[64][36];
  __shared__ float Ahi[32][68];
  const int lane = tid & 63, wq = tid >> 6;
  for (int f = tid; f < 512; f += 256) {
    int r = f >> 3, c = (f & 7) << 2;
    *(f32x4*)&Alo[r][c] = *(const f32x4*)&Al[r * 32 + c];
  }
  for (int f = tid; f < 512; f += 256) {
    int r = f >> 4, c = (f & 15) << 2;
    *(f32x4*)&Ahi[r][c] = *(const f32x4*)&Ah[r * 64 + c];
  }
  __syncthreads();
  {
    float ar[32];
#pragma unroll
    for (int r = 0; r < 32; r++) ar[r] = Alo[lane][r];
#pragma unroll
    for (int m4 = 0; m4 < 4; m4++) {
      f32x4 s = {0.f, 0.f, 0.f, 0.f};
#pragma unroll
      for (int r = 0; r < 32; r++)
        s += ar[r] * *(const f32x4*)&Ahi[r][wq * 16 + m4 * 4];
      *(f32x4*)&A[0][lane][wq * 16 + m4 * 4] = s;
    }
  }
  __syncthreads();
  for (int p = 1; p < 4; p++) {
    float ar[64];
#pragma unroll
    for (int k = 0; k < 64; k++) ar[k] = A[p - 1][lane][k];
#pragma unroll
    for (int m4 = 0; m4 < 4; m4++) {
      f32x4 s = {0.f, 0.f, 0.f, 0.f};
#pragma unroll
      for (int k = 0; k < 64; k++)
        s += ar[k] * *(const f32x4*)&A[0][k][wq * 16 + m4 * 4];
      *(f32x4*)&A[p][lane][wq * 16 + m4 * 4] = s;
    }
    __syncthreads();
  }
#pragma unroll
  for (int i = 0; i < 8; i++) {
    int e = tid + 256 * i;
    int kp = e >> 9, kk = (e >> 8) & 1, nt = (e >> 6) & 3, ln = e & 63;
    int n = nt * 16 + (ln & 15);
    int mc = kk * 32 + (ln >> 4) * 8;
    f32x4 a = *(const f32x4*)&A[kp][n][mc];
    f32x4 b = *(const f32x4*)&A[kp][n][mc + 4];
    *(u16x8*)&akbF[(size_t)e * 8] = __builtin_bit_cast(u16x8, cvt8(a, b));
  }
  if (wq == 0) {   // power iteration on A^T A
    float ar[64], at[64];
#pragma unroll
    for (int m = 0; m < 64; m++) { ar[m] = A[0][lane][m]; at[m] = A[0][m][lane]; }
    float v = 1.0f + 0.001f * (float)lane;
    for (int it = 0; it < 8; it++) {
      float w = 0.f;
#pragma unroll
      for (int m = 0; m < 64; m++) w += ar[m] * __shfl(v, m, 64);
      float z = 0.f;
#pragma unroll
      for (int m = 0; m < 64; m++) z += at[m] * __shfl(w, m, 64);
      float ss = z * z;
#pragma unroll
      for (int off = 32; off; off >>= 1) ss += __shfl_xor(ss, off, 64);
      v = z * rsqrtf(ss + 1e-38f);
    }
    float w = 0.f;
#pragma unroll
    for (int m = 0; m < 64; m++) w += ar[m] * __shfl(v, m, 64);
    float ss = w * w;
#pragma unroll
    for (int off = 32; off; off >>= 1) ss += __shfl_xor(ss, off, 64);
    if (lane == 0) *spec = sqrtf(ss);
  }
  if (wq == 1) {
    float dm = 0.f;
#pragma unroll
    for (int i = 0; i < 16; i++) dm = fmaxf(dm, fabsf(Dv[lane + i * 64]));
#pragma unroll
    for (int off = 32; off; off >>= 1) dm = fmaxf(dm, __shfl_xor(dm, off, 64));
    if (lane == 0) *dflag = dm;
  }
}

// ---------------------------------------------------------------------------
// G1 (split-K x2, swapped operands): u[t][n] = (x·Bw^T + Bb)[t][n] * rw[t]
// A-op = BwF (n rows), B-op = x (t cols)  ->  C: col=t, row=n  ->  f32x4
// epilogue stores along n. 512 threads: waves 0-3 = row tiles, K-low;
// waves 4-7 = same tiles, K-high; LDS reduce.
// ---------------------------------------------------------------------------
__global__ __launch_bounds__(512) void g1_gemm(const float* __restrict__ x,
                                               const unsigned short* __restrict__ BwF,
                                               const float* __restrict__ Bb,
                                               const float* __restrict__ rw,
                                               float* __restrict__ u) {
  __shared__ f32x4 accS[4][4][64];
  const int tid = threadIdx.x, lane = tid & 63, wid = tid >> 6;
  const int rt = wid & 3, kh = wid >> 2;
  const int t0 = blockIdx.x * 64 + rt * 16;
  const int trow = t0 + (lane & 15);
  const int q8 = (lane >> 4) * 8;
  f32x4 acc[4];
#pragma unroll
  for (int nt = 0; nt < 4; nt++) acc[nt] = f32x4{0.f, 0.f, 0.f, 0.f};
  const int ks0 = kh * 16;
#pragma unroll 4
  for (int ks = ks0; ks < ks0 + 16; ks++) {
    const float* xp = &x[(size_t)trow * 1024 + ks * 32 + q8];
    bf16x8 b = cvt8(*(const f32x4*)xp, *(const f32x4*)(xp + 4));
#pragma unroll
    for (int nt = 0; nt < 4; nt++) {
      bf16x8 a = ld_frag(&BwF[((size_t)(ks * 4 + nt) * 64 + lane) * 8]);
      acc[nt] = mfma16(a, b, acc[nt]);
    }
  }
  if (kh == 1) {
#pragma unroll
    for (int nt = 0; nt < 4; nt++) accS[rt][nt][lane] = acc[nt];
  }
  __syncthreads();
  if (kh == 0) {
    const float rwt = rw[trow];
#pragma unroll
    for (int nt = 0; nt < 4; nt++) {
      acc[nt] += accS[rt][nt][lane];
      int n0 = nt * 16 + (lane >> 4) * 4;
      f32x4 bb = *(const f32x4*)&Bb[n0];
      f32x4 o;
#pragma unroll
      for (int j = 0; j < 4; j++) o[j] = (acc[nt][j] + bb[j]) * rwt;
      *(f32x4*)&u[(size_t)trow * 64 + n0] = o;
    }
  }
}

// ---------------------------------------------------------------------------
// K2G2 fused (swapped operands): per wave, 16 t-rows.
// Phase 1: hs = u + sum_k A^k u_{t-k}  (A-op = akbF, B-op = u window;
//          C: col=t, row=n -> identity/u loads vectorized along n)
//          + batch-end state-norm atomicAdd.
// Phase 2: per-wave LDS transpose of hs (16x64 bf16) -> B-frag (col=t, k=n);
//          out = Cw·hs^T per 64-d chunk (A-op = CwF) -> f32x4 stores along d.
// No __syncthreads: hsT buffer is per-wave.
// ---------------------------------------------------------------------------
__global__ __launch_bounds__(256) void k2g2(const float* __restrict__ u,
                                            const unsigned short* __restrict__ akbF,
                                            const unsigned short* __restrict__ CwF,
                                            const float* __restrict__ Cb,
                                            const float* __restrict__ Dv,
                                            const float* __restrict__ x,
                                            const float* __restrict__ dflag,
                                            float* __restrict__ out,
                                            float* __restrict__ norm_out) {
  __shared__ unsigned short hsT[4][16][80];
  const int tid = threadIdx.x, lane = tid & 63, wid = tid >> 6;
  const int t0 = (blockIdx.x * 4 + wid) * 16;
  const int bstart = t0 & ~4095;
  const int trow = t0 + (lane & 15);
  const int q8 = (lane >> 4) * 8;
  f32x4 acc[4];
#pragma unroll
  for (int nt = 0; nt < 4; nt++) acc[nt] = f32x4{0.f, 0.f, 0.f, 0.f};
#pragma unroll
  for (int kp = 0; kp < 4; kp++) {
    int g = trow - (kp + 1);
#pragma unroll
    for (int kk = 0; kk < 2; kk++) {
      f32x4 xa = {0.f, 0.f, 0.f, 0.f}, xb = {0.f, 0.f, 0.f, 0.f};
      if (g >= bstart) {
        const float* up = &u[(size_t)g * 64 + kk * 32 + q8];
        xa = *(const f32x4*)up;
        xb = *(const f32x4*)(up + 4);
      }
      bf16x8 b = cvt8(xa, xb);
#pragma unroll
      for (int nt = 0; nt < 4; nt++) {
        bf16x8 a = ld_frag(&akbF[(size_t)(((kp * 2 + kk) * 4 + nt) * 64 + lane) * 8]);
        acc[nt] = mfma16(a, b, acc[nt]);
      }
    }
  }
  // identity (f32) + pack hs to LDS + batch-end norm
  const bool bend = ((t0 + 15) & 4095) == 4095;
  float ss = 0.f;
#pragma unroll
  for (int nt = 0; nt < 4; nt++) {
    int n0 = nt * 16 + (lane >> 4) * 4;
    f32x4 uid = *(const f32x4*)&u[(size_t)trow * 64 + n0];
    u16x4 pk;
#pragma unroll
    for (int j = 0; j < 4; j++) {
      float val = acc[nt][j] + uid[j];
      pk[j] = bf1(val);
      if (bend && (lane & 15) == 15) ss += val * val;
    }
    *(u16x4*)&hsT[wid][lane & 15][n0] = pk;
  }
  if (bend && (lane & 15) == 15) {
    ss += __shfl_xor(ss, 16, 64);
    ss += __shfl_xor(ss, 32, 64);
    if (lane == 15) atomicAdd(norm_out, sqrtf(ss) * 0.125f);
  }
  // hs B-frags (col=t=lane&15, k=n)
  bf16x8 hf[2];
#pragma unroll
  for (int kk = 0; kk < 2; kk++)
    hf[kk] = ld_frag(&hsT[wid][lane & 15][kk * 32 + q8]);
  const bool hasD = (*dflag != 0.0f);
  const size_t xrow = (size_t)trow * 1024;
#pragma unroll 2
  for (int dc = 0; dc < 16; dc++) {
    const int d0 = dc * 64;
    f32x4 o[4];
#pragma unroll
    for (int dt = 0; dt < 4; dt++) o[dt] = f32x4{0.f, 0.f, 0.f, 0.f};
#pragma unroll
    for (int kk = 0; kk < 2; kk++)
#pragma unroll
      for (int dt = 0; dt < 4; dt++) {
        bf16x8 a = ld_frag(&CwF[(size_t)((((d0 >> 4) + dt) * 2 + kk) * 64 + lane) * 8]);
        o[dt] = mfma16(a, hf[kk], o[dt]);
      }
#pragma unroll
    for (int dt = 0; dt < 4; dt++) {
      int db = d0 + dt * 16 + (lane >> 4) * 4;
      f32x4 cb = *(const f32x4*)&Cb[db];
      f32x4 v = o[dt] + cb;
      if (hasD) {
        f32x4 dd = *(const f32x4*)&Dv[db];
        f32x4 xv = *(const f32x4*)&x[xrow + db];
        v += dd * xv;
      }
      *(f32x4*)&out[xrow + db] = v;
    }
  }
}

extern "C" void kernel_launch(void* const* d_in, const int* in_sizes, int n_in,
                              void* d_out, int out_size, void* d_ws, size_t ws_size,
                              hipStream_t stream) {
  const float* x  = (const float*)d_in[0];
  const float* rw = (const float*)d_in[1];
  const float* Al = (const float*)d_in[2];
  const float* Ah = (const float*)d_in[3];
  const float* Bw = (const float*)d_in[4];
  const float* Bb = (const float*)d_in[5];
  const float* Cw = (const float*)d_in[6];
  const float* Cb = (const float*)d_in[7];
  const float* Dv = (const float*)d_in[8];
  float* out = (float*)d_out;

  char* ws = (char*)d_ws;
  unsigned short* akbF  = (unsigned short*)(ws);            // 32 KiB
  float*          dflag = (float*)(ws + 32768);             // 4 B
  unsigned short* BwF   = (unsigned short*)(ws + 65536);    // 128 KiB
  unsigned short* CwF   = (unsigned short*)(ws + 196608);   // 128 KiB
  float*          u     = (float*)(ws + 327680);            // 8 MiB

  float* norm_out = out + (out_size - 2);
  float* spec_out = out + (out_size - 1);

  kprep<<<dim3(65), dim3(256), 0, stream>>>(Bw, Cw, Al, Ah, Dv, BwF, CwF, akbF,
                                            dflag, spec_out);
  g1_gemm<<<dim3(512), dim3(512), 0, stream>>>(x, BwF, Bb, rw, u);
  hipMemsetAsync(norm_out, 0, sizeof(float), stream);
  k2g2<<<dim3(512), dim3(256), 0, stream>>>(u, akbF, CwF, Cb, Dv, x, dflag, out,
                                            norm_out);
}